// Round 15
// baseline (216.641 us; speedup 1.0000x reference)
//
#include <hip/hip_runtime.h>
#include <stdint.h>

// S=8, N=4096, F_IN=F_OUT=128
constexpr int N  = 4096;
constexpr int F  = 128;
constexpr int S  = 8;

typedef float f4  __attribute__((ext_vector_type(4)));
typedef short bf16x8 __attribute__((ext_vector_type(8)));
typedef unsigned short us4 __attribute__((ext_vector_type(4)));

__device__ __forceinline__ unsigned short f2bf(float f) {
  union { float f; unsigned int u; } v; v.f = f;
  unsigned int u = v.u + 0x7FFFu + ((v.u >> 16) & 1u);  // RNE
  return (unsigned short)(u >> 16);
}

__device__ __forceinline__ void bar_sync() {
  asm volatile("s_waitcnt lgkmcnt(0)" ::: "memory");
  __builtin_amdgcn_s_barrier();
  asm volatile("" ::: "memory");
}
__device__ __forceinline__ void vm_drain() {
  asm volatile("s_waitcnt vmcnt(0)" ::: "memory");
}
__device__ __forceinline__ void vm_wait1() {
  asm volatile("s_waitcnt vmcnt(1)" ::: "memory");
}

// async global->LDS, 16B/lane; LDS dest = wave-uniform base + lane*16.
__device__ __forceinline__ void gload_lds16(const void* g, void* l) {
  __builtin_amdgcn_global_load_lds(
      (const __attribute__((address_space(1))) void*)g,
      (__attribute__((address_space(3))) void*)l, 16, 0, 0);
}

// ---------------- kernel 0: xT[f][k] = bf16(x[k][f]) ----------------
__global__ __launch_bounds__(256, 2) void ggd_xt(
    const float* __restrict__ x, unsigned short* __restrict__ xT) {
  __shared__ float xl[64][132];
  const int t  = threadIdx.x;
  const int k0 = blockIdx.x * 64;
  {
    const int kr = t >> 2, fs = (t & 3) * 32;
    const float* src = x + (size_t)(k0 + kr) * F + fs;
#pragma unroll
    for (int i = 0; i < 8; ++i)
      *(f4*)&xl[kr][fs + i * 4] = *(const f4*)(src + i * 4);
  }
  __syncthreads();
  {
    const int f = t >> 1, kh = (t & 1) * 32;
    us4 o[8];
#pragma unroll
    for (int i = 0; i < 32; ++i)
      o[i >> 2][i & 3] = f2bf(xl[kh + i][f]);
    unsigned short* dst = xT + (size_t)f * N + k0 + kh;
#pragma unroll
    for (int j = 0; j < 8; ++j)
      *(us4*)(dst + j * 4) = o[j];
  }
}

// ---- kernel 1: slice-by-slice SWEEP qgen (chip-wide single stream) ----
// q stored bf16 row-major with k-swizzle: storage_us4[r][k4 ^ ((r&7)<<1)]
constexpr int QF4 = N / 4;              // 1024 f4 per row
constexpr int TOT = N * QF4;            // 4,194,304 f4
constexpr int POS = 8;                  // f4 positions per thread
constexpr int QG_BLOCKS = TOT / (256 * POS);   // 2048
constexpr int QG_STRIDE = 256 * QG_BLOCKS;     // 524288 f4

__global__ __launch_bounds__(256, 4) void ggd_qgen(
    const float* __restrict__ theta,
    const float* __restrict__ Ts,       // [S][N][N]
    const float* __restrict__ a,        // [N][N]
    unsigned short* __restrict__ q)     // [N][N] bf16, swizzled
{
  float th[S];
#pragma unroll
  for (int s = 0; s < S; ++s) th[s] = theta[s];

  const int tid = blockIdx.x * 256 + threadIdx.x;
  const f4* tf4 = (const f4*)Ts;
  const f4* af4 = (const f4*)a;
  us4* qs = (us4*)q;

  f4 acc[POS];
  // slice 0 initializes; slices 1..7 accumulate. s is the OUTER loop so the
  // whole chip sweeps ONE 64 MB slice at a time (sequential, coalesced).
#pragma unroll
  for (int s = 0; s < S; ++s) {
    f4 tv[POS];
#pragma unroll
    for (int ii = 0; ii < POS; ++ii)
      tv[ii] = tf4[(size_t)s * TOT + tid + ii * QG_STRIDE];
    if (s == 0) {
#pragma unroll
      for (int ii = 0; ii < POS; ++ii)
#pragma unroll
        for (int e = 0; e < 4; ++e)
          acc[ii][e] = th[0] * tv[ii][e];
    } else {
#pragma unroll
      for (int ii = 0; ii < POS; ++ii)
#pragma unroll
        for (int e = 0; e < 4; ++e)
          acc[ii][e] = fmaf(th[s], tv[ii][e], acc[ii][e]);
    }
  }
  // a sweep + pack + swizzled store
#pragma unroll
  for (int ii = 0; ii < POS; ++ii) {
    const int idx = tid + ii * QG_STRIDE;
    f4 av = af4[idx];
    us4 o;
#pragma unroll
    for (int e = 0; e < 4; ++e) o[e] = f2bf(av[e] * acc[ii][e]);
    const int r  = idx >> 10;
    const int k4 = idx & (QF4 - 1);
    qs[(size_t)r * QF4 + (k4 ^ ((r & 7) << 1))] = o;
  }
}

// ---- kernel 2: GEMM (q @ x) + PReLU + FC, BM=8, 512 blocks ----
constexpr int GBM = 8;
constexpr int GBK = 256;
constexpr int GNC = N / GBK;            // 16 chunks

__global__ __launch_bounds__(256, 2) void ggd_gemm(
    const unsigned short* __restrict__ q,   // [N][N] bf16, k-swizzled
    const unsigned short* __restrict__ xT,  // [F][N] bf16
    const float* __restrict__ W,            // [F][F] row-major [fo][fi]
    const float* __restrict__ bfc,          // [F]
    const float* __restrict__ alpha,        // [F]
    float* __restrict__ out)                // [N][F]
{
  __shared__ unsigned short qt[3][GBM][GBK];  // 12 KB triple-buffered
  __shared__ float p_lds[GBM][F];             // 4 KB epilogue

  const int t = threadIdx.x, wave = t >> 6, lane = t & 63;
  const int n0 = blockIdx.x * GBM;

  // stage chunk c: 4 KB = 4 x 1KB instrs, 1 per wave; instr w covers
  // storage rows {2w, 2w+1} x 512 B (swizzle is contained in 128 B groups)
  auto stage = [&](int c, int buf) {
    const int row = wave * 2 + (lane >> 5);
    const unsigned short* src =
        q + (size_t)(n0 + row) * N + c * GBK + (lane & 31) * 8;
    gload_lds16(src, &qt[buf][wave * 2][0]);
  };

  f4 acc[2];
#pragma unroll
  for (int i = 0; i < 2; ++i) acc[i] = (f4)(0.f);

  const int rr  = lane & 7;             // A row (rows 8-15 replicate 0-7)
  const int rsw = rr << 3;              // element-granular unswizzle key

  // prologue
  stage(0, 0);
  stage(1, 1);

  for (int c = 0; c < GNC; ++c) {
    const int buf = c % 3;
    if (c + 2 < GNC) stage(c + 2, (c + 2) % 3);

    // B-fragments from L2-hot xT: wave w -> f-tiles {2w, 2w+1}, 8 ksteps
    bf16x8 B[16];
#pragma unroll
    for (int i = 0; i < 2; ++i) {
      const unsigned short* fp =
          xT + (size_t)((wave * 2 + i) * 16 + (lane & 15)) * N + c * GBK +
          (lane >> 4) * 8;
#pragma unroll
      for (int h = 0; h < 8; ++h)
        B[i * 8 + h] = *(const bf16x8*)(fp + h * 32);
    }

    if (c == GNC - 1) vm_drain(); else vm_wait1();  // qt[buf] + B landed
    bar_sync();

#pragma unroll
    for (int h = 0; h < 8; ++h) {
      const int elem = (h * 32 + (lane >> 4) * 8) ^ rsw;
      bf16x8 af = *(const bf16x8*)&qt[buf][rr][elem];
      acc[0] = __builtin_amdgcn_mfma_f32_16x16x32_bf16(af, B[h],     acc[0], 0, 0, 0);
      acc[1] = __builtin_amdgcn_mfma_f32_16x16x32_bf16(af, B[8 + h], acc[1], 0, 0, 0);
    }
    bar_sync();   // all waves done reading qt[buf] before it is restaged
  }

  // ---- PReLU -> p_lds; C/D: col=lane&15, row=(lane>>4)*4+r (8-15 dup) ----
  if (lane < 32) {
#pragma unroll
    for (int i = 0; i < 2; ++i) {
      const int fo = (wave * 2 + i) * 16 + (lane & 15);
      const float al = alpha[fo];
#pragma unroll
      for (int r = 0; r < 4; ++r) {
        float v = acc[i][r];
        v = v >= 0.f ? v : al * v;
        p_lds[(lane >> 4) * 4 + r][fo] = v;
      }
    }
  }
  bar_sync();

  // ---- FC: out[n][fo] = b[fo] + sum_fi p[n][fi] * W[fo][fi] ----
  {
    const int r2  = t >> 5;             // 0..7
    const int fo0 = (t & 31) * 4;
    f4 accF = *(const f4*)(bfc + fo0);
#pragma unroll 4
    for (int fi4 = 0; fi4 < F / 4; ++fi4) {
      f4 pv = *(const f4*)&p_lds[r2][fi4 * 4];
#pragma unroll
      for (int e = 0; e < 4; ++e) {
        f4 wv = *(const f4*)(W + (size_t)(fo0 + e) * F + fi4 * 4);
        accF[e] = fmaf(pv[0], wv[0], fmaf(pv[1], wv[1],
                  fmaf(pv[2], wv[2], fmaf(pv[3], wv[3], accF[e]))));
      }
    }
    *(f4*)(out + (size_t)(n0 + r2) * F + fo0) = accF;
  }
}

// -------- fallback (ws too small): round-1 fused kernel --------
__global__ __launch_bounds__(256, 1) void ggd_fused_fb(
    const float* __restrict__ theta, const float* __restrict__ Ts,
    const float* __restrict__ x, const float* __restrict__ a,
    const float* __restrict__ W, const float* __restrict__ bfc,
    const float* __restrict__ alpha, float* __restrict__ out) {
  constexpr int BMf = 16, BKf = 64, NCF = N / BKf;
  __shared__ float q_l[2][BMf][BKf];
  __shared__ float p_l[BMf][F];
  const int t  = threadIdx.x;
  const int n0 = blockIdx.x * BMf;
  float th[S];
#pragma unroll
  for (int s = 0; s < S; ++s) th[s] = theta[s];
  const int qr = t >> 4, qk = (t & 15) << 2;
  const size_t rowOff = (size_t)(n0 + qr) * N, sliceSz = (size_t)N * N;
  const int tx = t & 31, ty = t >> 5;
  const int r0 = ty * 2, r1 = r0 + 1;
  f4 acc0 = (f4)(0.f), acc1 = (f4)(0.f);
  f4 tv[S]; f4 avv;
  auto loadc = [&](int c) {
    const size_t off = rowOff + (size_t)c * BKf + qk;
    avv = *(const f4*)(a + off);
#pragma unroll
    for (int s = 0; s < S; ++s)
      tv[s] = *(const f4*)(Ts + (size_t)s * sliceSz + off);
  };
  auto qstore = [&](int buf) {
    f4 qv;
#pragma unroll
    for (int j = 0; j < 4; ++j) {
      float sum = th[0] * tv[0][j];
#pragma unroll
      for (int s = 1; s < S; ++s) sum = fmaf(th[s], tv[s][j], sum);
      qv[j] = avv[j] * sum;
    }
    *(f4*)&q_l[buf][qr][qk] = qv;
  };
  loadc(0); qstore(0);
  for (int c = 0; c < NCF; ++c) {
    const int buf = c & 1;
    if (c + 1 < NCF) loadc(c + 1);
    bar_sync();
    const float* xp = x + (size_t)c * BKf * F + tx * 4;
#pragma unroll 4
    for (int kk4 = 0; kk4 < BKf / 4; ++kk4) {
      f4 q0 = *(const f4*)&q_l[buf][r0][kk4 * 4];
      f4 q1 = *(const f4*)&q_l[buf][r1][kk4 * 4];
#pragma unroll
      for (int j = 0; j < 4; ++j) {
        f4 xv = *(const f4*)(xp + (size_t)(kk4 * 4 + j) * F);
#pragma unroll
        for (int e = 0; e < 4; ++e) {
          acc0[e] = fmaf(q0[j], xv[e], acc0[e]);
          acc1[e] = fmaf(q1[j], xv[e], acc1[e]);
        }
      }
    }
    if (c + 1 < NCF) qstore(buf ^ 1);
  }
  {
    f4 al = *(const f4*)(alpha + tx * 4);
#pragma unroll
    for (int j = 0; j < 4; ++j) {
      acc0[j] = acc0[j] >= 0.f ? acc0[j] : al[j] * acc0[j];
      acc1[j] = acc1[j] >= 0.f ? acc1[j] : al[j] * acc1[j];
    }
  }
  *(f4*)&p_l[r0][tx * 4] = acc0;
  *(f4*)&p_l[r1][tx * 4] = acc1;
  bar_sync();
  const int rr = t >> 4, fo0 = (t & 15) * 8;
  float accF[8];
  {
    f4 b0 = *(const f4*)(bfc + fo0);
    f4 b1 = *(const f4*)(bfc + fo0 + 4);
#pragma unroll
    for (int j = 0; j < 4; ++j) { accF[j] = b0[j]; accF[4 + j] = b1[j]; }
  }
#pragma unroll 8
  for (int fi4 = 0; fi4 < F / 4; ++fi4) {
    f4 p4 = *(const f4*)&p_l[rr][fi4 * 4];
#pragma unroll
    for (int j = 0; j < 8; ++j) {
      f4 w4 = *(const f4*)(W + (size_t)(fo0 + j) * F + fi4 * 4);
      accF[j] = fmaf(p4[0], w4[0], fmaf(p4[1], w4[1],
                fmaf(p4[2], w4[2], fmaf(p4[3], w4[3], accF[j]))));
    }
  }
  f4 o0, o1;
#pragma unroll
  for (int j = 0; j < 4; ++j) { o0[j] = accF[j]; o1[j] = accF[4 + j]; }
  float* op = out + (size_t)(n0 + rr) * F + fo0;
  *(f4*)op       = o0;
  *(f4*)(op + 4) = o1;
}

extern "C" void kernel_launch(void* const* d_in, const int* in_sizes, int n_in,
                              void* d_out, int out_size, void* d_ws, size_t ws_size,
                              hipStream_t stream) {
  const float* theta = (const float*)d_in[0];
  const float* Ts    = (const float*)d_in[1];
  const float* x     = (const float*)d_in[2];
  const float* a     = (const float*)d_in[3];
  const float* W     = (const float*)d_in[4];
  const float* bfc   = (const float*)d_in[5];
  const float* alpha = (const float*)d_in[6];
  float* out = (float*)d_out;

  const size_t q_bytes  = (size_t)N * N * 2;   // 33.55 MB bf16
  const size_t xt_bytes = (size_t)N * F * 2;   // 1.05 MB bf16
  if (ws_size >= q_bytes + xt_bytes && d_ws != nullptr) {
    unsigned short* qbuf = (unsigned short*)d_ws;
    unsigned short* xT   = (unsigned short*)((char*)d_ws + q_bytes);
    ggd_xt  <<<dim3(N / 64),     dim3(256), 0, stream>>>(x, xT);
    ggd_qgen<<<dim3(QG_BLOCKS),  dim3(256), 0, stream>>>(theta, Ts, a, qbuf);
    ggd_gemm<<<dim3(N / GBM),    dim3(256), 0, stream>>>(qbuf, xT, W, bfc,
                                                         alpha, out);
  } else {
    ggd_fused_fb<<<dim3(N / 16), dim3(256), 0, stream>>>(
        theta, Ts, x, a, W, bfc, alpha, out);
  }
}

// Round 16
// 139.905 us; speedup vs baseline: 1.5485x; 1.5485x over previous
//
#include <hip/hip_runtime.h>
#include <stdint.h>

// S=8, N=4096, F_IN=F_OUT=128
constexpr int N  = 4096;
constexpr int F  = 128;
constexpr int S  = 8;
constexpr int BM = 16;              // rows per block (kernel1)
constexpr int KSPLIT = 8;
constexpr int KRANGE = N / KSPLIT;  // 512
constexpr int BK = 64;              // k-chunk
constexpr int NCH = KRANGE / BK;    // 8 chunks per block (even, >=4)
constexpr int NT = 256;

typedef float f4  __attribute__((ext_vector_type(4)));
typedef short bf16x8 __attribute__((ext_vector_type(8)));
typedef unsigned short us4 __attribute__((ext_vector_type(4)));

__device__ __forceinline__ unsigned short f2bf(float f) {
  union { float f; unsigned int u; } v; v.f = f;
  unsigned int u = v.u + 0x7FFFu + ((v.u >> 16) & 1u);  // RNE
  return (unsigned short)(u >> 16);
}

// Barrier that waits only on LDS ops.
__device__ __forceinline__ void bar_sync() {
  asm volatile("s_waitcnt lgkmcnt(0)" ::: "memory");
  __builtin_amdgcn_s_barrier();
  asm volatile("" ::: "memory");
}

__device__ __forceinline__ void vm_drain() {
  asm volatile("s_waitcnt vmcnt(0)" ::: "memory");
}
// steady-state: one iteration issues exactly 13 VMEM ops (8 rawT + 4 bfrag
// + 1 a); allowing 13 outstanding waits for everything issued one full
// iteration earlier.
__device__ __forceinline__ void vm_wait13() {
  asm volatile("s_waitcnt vmcnt(13)" ::: "memory");
}
// tail iteration (c = NCH-2) issues only the 4 bfrag loads.
__device__ __forceinline__ void vm_wait4() {
  asm volatile("s_waitcnt vmcnt(4)" ::: "memory");
}

// async global->LDS, 16B/lane; LDS dest = wave-uniform base + lane*16.
__device__ __forceinline__ void gload_lds16(const void* g, void* l) {
  __builtin_amdgcn_global_load_lds(
      (const __attribute__((address_space(1))) void*)g,
      (__attribute__((address_space(3))) void*)l, 16, 0, 0);
}

struct BSet { bf16x8 v[4]; };   // [i][h] -> v[i*2+h], always static-indexed

// ---------------- kernel 0: xT[f][k] = bf16(x[k][f]) ----------------
__global__ __launch_bounds__(256, 2) void ggd_xt(
    const float* __restrict__ x, unsigned short* __restrict__ xT) {
  __shared__ float xl[64][132];       // +4 pad: conflict-free column reads
  const int t  = threadIdx.x;
  const int k0 = blockIdx.x * 64;

  {
    const int kr = t >> 2, fs = (t & 3) * 32;
    const float* src = x + (size_t)(k0 + kr) * F + fs;
#pragma unroll
    for (int i = 0; i < 8; ++i)
      *(f4*)&xl[kr][fs + i * 4] = *(const f4*)(src + i * 4);
  }
  __syncthreads();
  {
    const int f = t >> 1, kh = (t & 1) * 32;
    us4 o[8];
#pragma unroll
    for (int i = 0; i < 32; ++i)
      o[i >> 2][i & 3] = f2bf(xl[kh + i][f]);
    unsigned short* dst = xT + (size_t)f * N + k0 + kh;
#pragma unroll
    for (int j = 0; j < 8; ++j)
      *(us4*)(dst + j * 4) = o[j];
  }
}

// -------- kernel 1: q-gen + MFMA q@x partials, depth-2 pipeline --------
template <bool USE_WS>
__global__ __launch_bounds__(NT, 2) void ggd_diffuse(
    const float* __restrict__ theta,
    const float* __restrict__ Ts,     // [S][N][N]
    const unsigned short* __restrict__ xT,  // [F][N] bf16
    const float* __restrict__ a,      // [N][N]
    float* __restrict__ dst)          // ws [KSPLIT][N][F] or out [N][F]
{
  __shared__ float rawT[2][S][BM][BK];        // 64 KB double-buffered
  __shared__ unsigned short q_lds[2][BM][BK]; //  4 KB double-buffered (bf16)

  const int t  = threadIdx.x;
  const int rb = blockIdx.x >> 3;     // 0..255 row block
  const int ks = blockIdx.x & 7;      // 0..7   k-split (~XCD-local xT slice)
  const int n0 = rb * BM;
  const int k0 = ks * KRANGE;

  float th[S];
#pragma unroll
  for (int s = 0; s < S; ++s) th[s] = theta[s];

  const int wave = t >> 6, lane = t & 63;
  const size_t slice = (size_t)N * N;

  // qgen mapping: thread t -> row t>>4 (0..15), cols (t&15)*4 .. +3
  const int qr = t >> 4;
  const int qk = (t & 15) * 4;

  f4 acc[2];
#pragma unroll
  for (int i = 0; i < 2; ++i) acc[i] = (f4)(0.f);

  // rawT: 32 KB/chunk = 32 x 1KB instrs (8/wave); instr i: slice i>>2,
  // rows (i&3)*4..+3, each row 64 floats = 256 B contiguous.
  auto stage_rawT = [&](int c, int buf) {
    const int grow = lane >> 4;          // 0..3
    const size_t cb = (size_t)(k0 + c * BK) + (lane & 15) * 4;
#pragma unroll
    for (int j = 0; j < 8; ++j) {
      const int i = wave * 8 + j;        // 0..31
      const int s  = i >> 2;
      const int r4 = (i & 3) * 4;
      const float* src = Ts + (size_t)s * slice +
                         (size_t)(n0 + r4 + grow) * N + cb;
      gload_lds16(src, &rawT[buf][0][0][0] + i * 256);
    }
  };

  // B-fragments for chunk c from global (L2-hot 128 KB/XCD slice): 4 x 16B.
  auto bfrag_load = [&](int c, BSet& B) {
    const int kc = k0 + c * BK;
#pragma unroll
    for (int i = 0; i < 2; ++i) {
      const int fr = (wave * 2 + i) * 16 + (lane & 15);
#pragma unroll
      for (int h = 0; h < 2; ++h)
        B.v[i * 2 + h] = *(const bf16x8*)(xT + (size_t)fr * N + kc + h * 32 +
                                          (lane >> 4) * 8);
    }
  };

  auto load_a = [&](int c) -> f4 {
    return *(const f4*)(a + (size_t)(n0 + qr) * N + (k0 + c * BK + qk));
  };

  // q[c1&1][qr][qk..+3] = bf16( a * sum_s th[s]*T[s] ), from rawT[c1&1]
  auto qgen = [&](int c1, f4 av) {
    const float* rt = &rawT[c1 & 1][0][qr][qk];
    f4 sum;
    {
      f4 tv = *(const f4*)rt;
#pragma unroll
      for (int j = 0; j < 4; ++j) sum[j] = th[0] * tv[j];
    }
#pragma unroll
    for (int s = 1; s < S; ++s) {
      f4 tv = *(const f4*)(rt + (size_t)s * (BM * BK));
#pragma unroll
      for (int j = 0; j < 4; ++j) sum[j] = fmaf(th[s], tv[j], sum[j]);
    }
    us4 q;
#pragma unroll
    for (int j = 0; j < 4; ++j) q[j] = f2bf(av[j] * sum[j]);
    *(us4*)&q_lds[c1 & 1][qr][qk] = q;   // ds_write_b64
  };

  // 4 MFMA: A = q[16][64] k-halves, B = reg fragments.
  auto compute = [&](int c, const BSet& B) {
    const unsigned short* qb = &q_lds[c & 1][0][0];
#pragma unroll
    for (int h = 0; h < 2; ++h) {
      bf16x8 af = *(const bf16x8*)(qb + (lane & 15) * BK + h * 32 +
                                   (lane >> 4) * 8);
#pragma unroll
      for (int i = 0; i < 2; ++i)
        acc[i] = __builtin_amdgcn_mfma_f32_16x16x32_bf16(af, B.v[i * 2 + h],
                                                         acc[i], 0, 0, 0);
    }
  };

  f4 avE, avO;
  BSet bE, bO;

  // ---- prologue: chunks 0,1 staged; bfrag(0); a(0),a(1) ----
  stage_rawT(0, 0);
  stage_rawT(1, 1);
  bfrag_load(0, bE);
  avE = load_a(0);
  avO = load_a(1);
  vm_drain();
  bar_sync();
  qgen(0, avE);
  bar_sync();

  // ---- steady state: depth-2 counted vmcnt, race-free ordering:
  //      issue -> wait(own prev iter) -> barrier(all waves certified)
  //      -> compute(c) + qgen(c+1) -> barrier(publish q[c+1]) ----
  for (int cc = 0; cc + 1 < NCH - 2; cc += 2) {   // cc = 0,2,4
    {
      const int c = cc;                 // even
      stage_rawT(c + 2, c & 1);
      bfrag_load(c + 1, bO);
      avE = load_a(c + 2);
      vm_wait13();                      // my iter-(c-1) loads landed
      bar_sync();                       // => ALL waves' rawT(c+1) landed
      compute(c, bE);
      qgen(c + 1, avO);
      bar_sync();                       // publish q[(c+1)&1]
    }
    {
      const int c = cc + 1;             // odd
      stage_rawT(c + 2, c & 1);
      bfrag_load(c + 1, bE);
      avO = load_a(c + 2);
      vm_wait13();
      bar_sync();
      compute(c, bO);
      qgen(c + 1, avE);
      bar_sync();
    }
  }

  // ---- tail: c = NCH-2 (even), then c = NCH-1 ----
  {
    const int c = NCH - 2;
    bfrag_load(c + 1, bO);
    vm_wait4();                         // prior iteration's 13 landed
    bar_sync();
    compute(c, bE);
    qgen(c + 1, avO);
    bar_sync();
  }
  compute(NCH - 1, bO);                 // bfrag reg-dep waited by compiler

  // ---- write partials; C/D: col=lane&15, row=(lane>>4)*4+reg ----
  const int crow = n0 + (lane >> 4) * 4;
  const int ccol = lane & 15;
#pragma unroll
  for (int i = 0; i < 2; ++i) {
    const int fo = (wave * 2 + i) * 16 + ccol;
#pragma unroll
    for (int r = 0; r < 4; ++r) {
      const size_t row = (size_t)(crow + r);
      if (USE_WS) {
        dst[((size_t)ks * N + row) * F + fo] = acc[i][r];
      } else {
        atomicAdd(dst + row * F + fo, acc[i][r]);
      }
    }
  }
}

// ---------------- kernel 2: (reduce) + PReLU + FC ----------------
template <bool USE_WS>
__global__ __launch_bounds__(256, 2) void ggd_fc(
    const float* __restrict__ W,      // [F][F] row-major [fo][fi]
    const float* __restrict__ bfc,    // [F]
    const float* __restrict__ alpha,  // [F]
    const float* __restrict__ src,    // ws [KSPLIT][N][F] or out [N][F]
    float* __restrict__ out)          // [N][F]
{
  __shared__ float p_lds[16 * F];     // 8 KB
  const int t  = threadIdx.x;
  const int n0 = blockIdx.x * 16;

  {
    const int lr = t >> 4, c8 = (t & 15) * 8;
    f4 v0, v1;
    if (USE_WS) {
      v0 = (f4)(0.f); v1 = (f4)(0.f);
#pragma unroll
      for (int ks = 0; ks < KSPLIT; ++ks) {
        const float* sp = src + ((size_t)ks * N + n0 + lr) * F + c8;
        v0 += *(const f4*)(sp);
        v1 += *(const f4*)(sp + 4);
      }
    } else {
      const float* ip = src + (size_t)(n0 + lr) * F + c8;
      v0 = *(const f4*)(ip);
      v1 = *(const f4*)(ip + 4);
    }
    f4 a0 = *(const f4*)(alpha + c8);
    f4 a1 = *(const f4*)(alpha + c8 + 4);
#pragma unroll
    for (int j = 0; j < 4; ++j) {
      v0[j] = v0[j] >= 0.f ? v0[j] : a0[j] * v0[j];
      v1[j] = v1[j] >= 0.f ? v1[j] : a1[j] * v1[j];
    }
    *(f4*)&p_lds[lr * F + c8]     = v0;
    *(f4*)&p_lds[lr * F + c8 + 4] = v1;
  }
  __syncthreads();

  const int r2  = t >> 5;             // 0..7
  const int fo0 = (t & 31) * 4;
  f4 accA = *(const f4*)(bfc + fo0);
  f4 accB = accA;
#pragma unroll 4
  for (int fi4 = 0; fi4 < F / 4; ++fi4) {
    f4 pA = *(const f4*)&p_lds[r2 * F + fi4 * 4];
    f4 pB = *(const f4*)&p_lds[(r2 + 8) * F + fi4 * 4];
#pragma unroll
    for (int e = 0; e < 4; ++e) {
      f4 wv = *(const f4*)(W + (size_t)(fo0 + e) * F + fi4 * 4);
      accA[e] = fmaf(pA[0], wv[0], fmaf(pA[1], wv[1],
                fmaf(pA[2], wv[2], fmaf(pA[3], wv[3], accA[e]))));
      accB[e] = fmaf(pB[0], wv[0], fmaf(pB[1], wv[1],
                fmaf(pB[2], wv[2], fmaf(pB[3], wv[3], accB[e]))));
    }
  }
  *(f4*)(out + (size_t)(n0 + r2) * F + fo0)     = accA;
  *(f4*)(out + (size_t)(n0 + r2 + 8) * F + fo0) = accB;
}

extern "C" void kernel_launch(void* const* d_in, const int* in_sizes, int n_in,
                              void* d_out, int out_size, void* d_ws, size_t ws_size,
                              hipStream_t stream) {
  const float* theta = (const float*)d_in[0];
  const float* Ts    = (const float*)d_in[1];
  const float* x     = (const float*)d_in[2];
  const float* a     = (const float*)d_in[3];
  const float* W     = (const float*)d_in[4];
  const float* bfc   = (const float*)d_in[5];
  const float* alpha = (const float*)d_in[6];
  float* out = (float*)d_out;

  const size_t part_bytes = (size_t)KSPLIT * N * F * sizeof(float);  // 16.8 MB
  const size_t xt_bytes   = (size_t)N * F * 2;                       // 1 MB
  if (ws_size >= part_bytes + xt_bytes && d_ws != nullptr) {
    float* parts = (float*)d_ws;
    unsigned short* xT = (unsigned short*)((char*)d_ws + part_bytes);
    ggd_xt<<<dim3(N / 64), dim3(256), 0, stream>>>(x, xT);
    ggd_diffuse<true><<<dim3((N / BM) * KSPLIT), dim3(NT), 0, stream>>>(
        theta, Ts, xT, a, parts);
    ggd_fc<true><<<dim3(N / 16), dim3(256), 0, stream>>>(
        W, bfc, alpha, parts, out);
  } else {
    // fallback: atomic accumulation into out (needs only 1 MB ws for xT)
    unsigned short* xT = (unsigned short*)d_ws;
    hipMemsetAsync(out, 0, (size_t)out_size * sizeof(float), stream);
    ggd_xt<<<dim3(N / 64), dim3(256), 0, stream>>>(x, xT);
    ggd_diffuse<false><<<dim3((N / BM) * KSPLIT), dim3(NT), 0, stream>>>(
        theta, Ts, xT, a, out);
    ggd_fc<false><<<dim3(N / 16), dim3(256), 0, stream>>>(
        W, bfc, alpha, out, out);
  }
}